// Round 1
// baseline (1759.593 us; speedup 1.0000x reference)
//
#include <hip/hip_runtime.h>
#include <math.h>

#define TPB 256

constexpr int kNFFT   = 1024;
constexpr int kHop    = 320;
constexpr int kBins   = 513;            // N_FFT/2 + 1
constexpr int kNC     = 1026;           // 2 * kBins
constexpr int kMels   = 128;
constexpr int kFrames = 1000;
constexpr int kBatch  = 32;
constexpr int kXLen   = 320000;
constexpr int kYLen   = kXLen - 1;      // 319999
constexpr int kTT     = 8;              // frames per block
constexpr int kTiles  = kFrames / kTT;  // 125
constexpr int kYBuf   = (kTT - 1) * kHop + kNFFT; // 3264
constexpr int kBTS    = 1028;           // basisT row stride (floats), 16B-aligned
constexpr float kPre  = 0.97f;

// Prep: transpose fourier basis [1026][1024] -> bT [1024][1028-padded]
// idx is n-major so writes (c contiguous) are coalesced; reads hit L2 (4.2MB).
__global__ void transpose_basis(const float* __restrict__ basis, float* __restrict__ bT) {
    int idx = blockIdx.x * TPB + threadIdx.x;
    if (idx >= kNFFT * kNC) return;
    int n = idx / kNC;
    int c = idx - n * kNC;
    bT[n * kBTS + c] = basis[c * kNFFT + n];
}

// Fused: pre-emphasis + framing + STFT dot + power + mel + log for one
// (batch, 8-frame tile). 256 threads; thread owns fourier rows c=4*tid..4*tid+3.
__global__ __launch_bounds__(TPB)
void stft_mel(const float* __restrict__ x, const float* __restrict__ bT,
              const float* __restrict__ melb, float* __restrict__ out) {
    __shared__ __align__(16) float sh[kNC * kTT];  // 32832 B; first 3264 = ybuf
    const int tid  = threadIdx.x;
    const int tile = blockIdx.x;
    const int b    = blockIdx.y;
    const int t0   = tile * kTT;
    const float* xb = x + b * kXLen;

    // ---- stage pre-emphasized, center-padded signal segment into LDS ----
    const int base = t0 * kHop - (kNFFT / 2);
    for (int i = tid; i < kYBuf; i += TPB) {
        int g = base + i;
        float v = 0.0f;
        if (g >= 0 && g < kYLen) v = xb[g + 1] - kPre * xb[g];
        sh[i] = v;
    }
    __syncthreads();

    // ---- STFT: acc[j][t] = dot(basis[c0+j], frame t) ----
    float acc[4][kTT];
    #pragma unroll
    for (int j = 0; j < 4; ++j)
        #pragma unroll
        for (int t = 0; t < kTT; ++t) acc[j][t] = 0.0f;
    float acce[kTT];
    #pragma unroll
    for (int t = 0; t < kTT; ++t) acce[t] = 0.0f;

    const float4* bT4 = (const float4*)bT;
    for (int n = 0; n < kNFFT; n += 4) {
        float4 yv[kTT];
        #pragma unroll
        for (int t = 0; t < kTT; ++t)
            yv[t] = *(const float4*)&sh[t * kHop + n];   // broadcast b128 reads
        #pragma unroll
        for (int q = 0; q < 4; ++q) {
            float4 bv = bT4[(n + q) * (kBTS / 4) + tid]; // coalesced 1KB/wave
            #pragma unroll
            for (int t = 0; t < kTT; ++t) {
                float y = ((const float*)yv)[t * 4 + q];
                acc[0][t] = fmaf(bv.x, y, acc[0][t]);
                acc[1][t] = fmaf(bv.y, y, acc[1][t]);
                acc[2][t] = fmaf(bv.z, y, acc[2][t]);
                acc[3][t] = fmaf(bv.w, y, acc[3][t]);
            }
            if (tid < 2) {  // rows 1024,1025 (imag bins 511,512) — wave 0 only
                float be = bT[(n + q) * kBTS + 1024 + tid];
                #pragma unroll
                for (int t = 0; t < kTT; ++t)
                    acce[t] = fmaf(be, ((const float*)yv)[t * 4 + q], acce[t]);
            }
        }
    }
    __syncthreads();   // done reading ybuf; reuse LDS for spec

    // ---- spec -> LDS, layout sh[c*8 + t] ----
    #pragma unroll
    for (int j = 0; j < 4; ++j)
        #pragma unroll
        for (int t = 0; t < kTT; ++t)
            sh[(tid * 4 + j) * kTT + t] = acc[j][t];
    if (tid < 2) {
        #pragma unroll
        for (int t = 0; t < kTT; ++t)
            sh[(1024 + tid) * kTT + t] = acce[t];
    }
    __syncthreads();

    // ---- power in-place: sh[f*8+t] = re^2 + im^2 ----
    for (int i = tid; i < kBins * kTT; i += TPB) {
        float re = sh[i];
        float im = sh[i + kBins * kTT];
        sh[i] = fmaf(re, re, im * im);
    }
    __syncthreads();

    // ---- mel + log: thread -> (m0 + 32j, tt) ----
    const int tt = tid & 7;
    const int m0 = tid >> 3;
    float mac[4] = {0.f, 0.f, 0.f, 0.f};
    for (int f = 0; f < kBins; ++f) {
        float p = sh[f * kTT + tt];
        #pragma unroll
        for (int j = 0; j < 4; ++j)
            mac[j] = fmaf(melb[(m0 + 32 * j) * kBins + f], p, mac[j]);
    }
    #pragma unroll
    for (int j = 0; j < 4; ++j) {
        int m = m0 + 32 * j;
        out[(b * kMels + m) * kFrames + t0 + tt] = (logf(mac[j] + 1e-5f) + 4.5f) * 0.2f;
    }
}

extern "C" void kernel_launch(void* const* d_in, const int* in_sizes, int n_in,
                              void* d_out, int out_size, void* d_ws, size_t ws_size,
                              hipStream_t stream) {
    const float* x     = (const float*)d_in[0];
    const float* basis = (const float*)d_in[1];
    const float* melb  = (const float*)d_in[2];
    float* out = (float*)d_out;
    float* bT  = (float*)d_ws;   // 1024*1028*4 = 4.21 MB

    int total = kNFFT * kNC;
    transpose_basis<<<dim3((total + TPB - 1) / TPB), TPB, 0, stream>>>(basis, bT);

    dim3 grid(kTiles, kBatch);
    stft_mel<<<grid, TPB, 0, stream>>>(x, bT, melb, out);
}

// Round 2
// 537.263 us; speedup vs baseline: 3.2751x; 3.2751x over previous
//
#include <hip/hip_runtime.h>
#include <math.h>

typedef short bf16x8 __attribute__((ext_vector_type(8)));
typedef float f32x4 __attribute__((ext_vector_type(4)));

constexpr int kNFFT    = 1024;
constexpr int kHop     = 320;
constexpr int kBins    = 513;
constexpr int kMels    = 128;
constexpr int kFrames  = 1000;
constexpr int kBatch   = 32;
constexpr int kXLen    = 320000;
constexpr int kYLen    = kXLen - 1;          // 319999
constexpr int kYPad    = 328704;             // per-batch padded y length (>= 1023*320+1024, mult of 256)
constexpr int kYOff    = 512;                // center-pad offset
constexpr float kPre   = 0.97f;

// ws layout (bytes)
constexpr size_t kYpadBytes  = 3ull * kBatch * kYPad * 2;            // 63,111,168
constexpr size_t kFragOff    = kYpadBytes;
constexpr size_t kFragLvl    = 64ull * 32 * 64 * 8;                  // shorts per level = 1,048,576
constexpr size_t kFragBytes  = 3ull * kFragLvl * 2;                  // 6,291,456
constexpr size_t kMelTOff    = kFragOff + kFragBytes;                // 69,402,624
constexpr size_t kMelTBytes  = 513ull * 128 * 4;                     // 262,656
constexpr size_t kPowOff     = kMelTOff + kMelTBytes;                // 69,665,280 (16B aligned)

__device__ __forceinline__ unsigned short f2bf(float v) {
    unsigned int u = __float_as_uint(v);
    unsigned int r = (u + 0x7fffu + ((u >> 16) & 1u)) >> 16;
    return (unsigned short)r;
}
__device__ __forceinline__ float bf2f(unsigned short h) {
    return __uint_as_float(((unsigned int)h) << 16);
}

// ---- prep 1: pre-emphasis + center pad, 3-level bf16 split ----
__global__ void prep_y(const float* __restrict__ x, unsigned short* __restrict__ yp) {
    int i = blockIdx.x * 256 + threadIdx.x;
    if (i >= kYPad) return;
    int b = blockIdx.y;
    int yi = i - kYOff;
    float v = 0.0f;
    if (yi >= 0 && yi < kYLen) {
        const float* xb = x + (size_t)b * kXLen;
        v = xb[yi + 1] - kPre * xb[yi];
    }
    unsigned short h = f2bf(v);
    float rm = v - bf2f(h);
    unsigned short m = f2bf(rm);
    float rl = rm - bf2f(m);
    unsigned short l = f2bf(rl);
    size_t idx = (size_t)b * kYPad + i;
    yp[idx] = h;
    yp[idx + (size_t)kBatch * kYPad] = m;
    yp[idx + 2ull * kBatch * kYPad] = l;
}

// ---- prep 2: pack fourier basis into MFMA A-fragments, 3-level split ----
// packed rows: 0..512 = cos bins 0..512 (orig rows 0..512)
//              513..1023 = sin bins 1..511 (orig rows 514..1024)
// frag[level][g][ks][lane][j] : A[m=lane&15 within group g][k=32ks+(lane>>4)*8+j]
__global__ void prep_frags(const float* __restrict__ basis, unsigned short* __restrict__ fr) {
    int id = blockIdx.x * 256 + threadIdx.x;      // < 131072
    int L  = id & 63;
    int ks = (id >> 6) & 31;
    int g  = id >> 11;                            // 0..63
    int r  = 16 * g + (L & 15);                   // packed row
    int orig = (r <= 512) ? r : r + 1;
    const float* src = basis + (size_t)orig * kNFFT + 32 * ks + (L >> 4) * 8;
    unsigned short* dst = fr + (size_t)id * 8;    // id == (g*32+ks)*64+L
    #pragma unroll
    for (int j = 0; j < 8; ++j) {
        float a = src[j];
        unsigned short h = f2bf(a);
        float rm = a - bf2f(h);
        unsigned short m = f2bf(rm);
        float rl = rm - bf2f(m);
        unsigned short l = f2bf(rl);
        dst[j] = h;
        dst[j + kFragLvl] = m;
        dst[j + 2 * kFragLvl] = l;
    }
}

// ---- prep 3: transpose mel basis [128][513] -> [513][128] fp32 ----
__global__ void prep_melT(const float* __restrict__ melb, float* __restrict__ mt) {
    int id = blockIdx.x * 256 + threadIdx.x;
    if (id >= 513 * 128) return;
    int f = id >> 7, m = id & 127;
    mt[id] = melb[(size_t)m * 513 + f];
}

// ---- main: 6-term split-bf16 MFMA STFT + power ----
// block: (nt, g, b). M = rows {64g..64g+63} U {512+64g..+63}; N = 128 frames.
// wave tile: M=128 x N=32. power[b][bin][t(1024 pad)] bf16.
__global__ __launch_bounds__(256)
void stft_power(const unsigned short* __restrict__ frags,
                const unsigned short* __restrict__ ypad,
                unsigned short* __restrict__ power) {
    __shared__ __align__(16) unsigned short ash[24 * 512];   // 24 frags x 1KB
    const int tid  = threadIdx.x;
    const int w    = tid >> 6;
    const int lane = tid & 63;
    const int quad = lane >> 4;
    const int l16  = lane & 15;
    const int nt = blockIdx.x, g = blockIdx.y, b = blockIdx.z;
    const int t0 = nt * 128 + w * 32;

    const unsigned short* yb0 = ypad + (size_t)b * kYPad;
    const unsigned short* yb1 = yb0 + (size_t)kBatch * kYPad;
    const unsigned short* yb2 = yb0 + 2ull * kBatch * kYPad;

    f32x4 acc[8][2] = {};

    for (int ks = 0; ks < 32; ++ks) {
        __syncthreads();
        // stage 24 A-frags: wave w handles slots {w, w+4, ..., w+20}
        #pragma unroll
        for (int c = 0; c < 6; ++c) {
            int slot = w + 4 * c;
            int f = slot & 7;
            int lv = slot >> 3;
            int Gf = (f < 4) ? (4 * g + f) : (32 + 4 * g + (f - 4));
            const unsigned short* gp = frags + (size_t)lv * kFragLvl
                                     + ((size_t)(Gf * 32 + ks) * 64 + lane) * 8;
            __builtin_amdgcn_global_load_lds(
                (const __attribute__((address_space(1))) void*)gp,
                (__attribute__((address_space(3))) void*)&ash[slot * 512],
                16, 0, 0);
        }
        // B fragments (direct from global/L2)
        bf16x8 bh[2], bm[2], bl[2];
        #pragma unroll
        for (int nf = 0; nf < 2; ++nf) {
            int off = (t0 + nf * 16 + l16) * kHop + ks * 32 + quad * 8;
            bh[nf] = *(const bf16x8*)(yb0 + off);
            bm[nf] = *(const bf16x8*)(yb1 + off);
            bl[nf] = *(const bf16x8*)(yb2 + off);
        }
        __syncthreads();   // drains global_load_lds (vmcnt) per wave + barrier
        #pragma unroll
        for (int f = 0; f < 8; ++f) {
            bf16x8 afh = *(const bf16x8*)&ash[(f) * 512 + lane * 8];
            bf16x8 afm = *(const bf16x8*)&ash[(8 + f) * 512 + lane * 8];
            bf16x8 afl = *(const bf16x8*)&ash[(16 + f) * 512 + lane * 8];
            #pragma unroll
            for (int nf = 0; nf < 2; ++nf) {
                f32x4 a = acc[f][nf];
                a = __builtin_amdgcn_mfma_f32_16x16x32_bf16(afh, bh[nf], a, 0, 0, 0);
                a = __builtin_amdgcn_mfma_f32_16x16x32_bf16(afh, bm[nf], a, 0, 0, 0);
                a = __builtin_amdgcn_mfma_f32_16x16x32_bf16(afm, bh[nf], a, 0, 0, 0);
                a = __builtin_amdgcn_mfma_f32_16x16x32_bf16(afh, bl[nf], a, 0, 0, 0);
                a = __builtin_amdgcn_mfma_f32_16x16x32_bf16(afm, bm[nf], a, 0, 0, 0);
                a = __builtin_amdgcn_mfma_f32_16x16x32_bf16(afl, bh[nf], a, 0, 0, 0);
                acc[f][nf] = a;
            }
        }
    }

    // epilogue: power = cos^2 + sin^2 (chunkA f=0..3, chunkB f=4..7 pair elementwise)
    #pragma unroll
    for (int mf = 0; mf < 4; ++mf) {
        #pragma unroll
        for (int nf = 0; nf < 2; ++nf) {
            int t = t0 + nf * 16 + l16;
            #pragma unroll
            for (int r = 0; r < 4; ++r) {
                float pA = acc[mf][nf][r];
                float pB = acc[4 + mf][nf][r];
                int bin = 64 * g + 16 * mf + 4 * quad + r;
                float p2 = pA * pA + pB * pB;
                if (g == 0 && mf == 0 && r == 0 && quad == 0) {
                    // bin 0: im == 0; chunkB row here is cos bin 512
                    p2 = pA * pA;
                    power[((size_t)(b * 513 + 512) << 10) + t] = f2bf(pB * pB);
                }
                power[((size_t)(b * 513 + bin) << 10) + t] = f2bf(p2);
            }
        }
    }
}

// ---- mel + log: fp32 VALU ----
// block: (tt, b) -> 32 frames. thread: m = tid&127, th = tid>>7 -> 16 frames.
__global__ __launch_bounds__(256)
void mel_log(const unsigned short* __restrict__ power, const float* __restrict__ melT,
             float* __restrict__ out) {
    const int tid = threadIdx.x;
    const int m = tid & 127;
    const int th = tid >> 7;
    const int tt = blockIdx.x;
    const int b = blockIdx.y;
    const int t0 = tt * 32 + th * 16;
    const unsigned short* pb = power + ((size_t)b * 513 << 10) + t0;
    float acc[16] = {};
    for (int f = 0; f < 513; ++f) {
        float wgt = melT[f * 128 + m];
        const uint4* pr = (const uint4*)(pb + ((size_t)f << 10));
        #pragma unroll
        for (int h = 0; h < 2; ++h) {
            uint4 u = pr[h];
            unsigned int uu[4] = {u.x, u.y, u.z, u.w};
            #pragma unroll
            for (int k = 0; k < 4; ++k) {
                int e = h * 8 + 2 * k;
                acc[e]     = fmaf(wgt, __uint_as_float(uu[k] << 16), acc[e]);
                acc[e + 1] = fmaf(wgt, __uint_as_float(uu[k] & 0xFFFF0000u), acc[e + 1]);
            }
        }
    }
    float* ob = out + ((size_t)(b * kMels + m)) * kFrames + t0;
    #pragma unroll
    for (int j = 0; j < 4; ++j) {
        if (t0 + 4 * j + 3 < kFrames) {
            float4 o;
            o.x = (__logf(acc[4 * j + 0] + 1e-5f) + 4.5f) * 0.2f;
            o.y = (__logf(acc[4 * j + 1] + 1e-5f) + 4.5f) * 0.2f;
            o.z = (__logf(acc[4 * j + 2] + 1e-5f) + 4.5f) * 0.2f;
            o.w = (__logf(acc[4 * j + 3] + 1e-5f) + 4.5f) * 0.2f;
            *(float4*)(ob + 4 * j) = o;
        }
    }
}

extern "C" void kernel_launch(void* const* d_in, const int* in_sizes, int n_in,
                              void* d_out, int out_size, void* d_ws, size_t ws_size,
                              hipStream_t stream) {
    const float* x     = (const float*)d_in[0];
    const float* basis = (const float*)d_in[1];
    const float* melb  = (const float*)d_in[2];
    float* out = (float*)d_out;

    unsigned short* ypad  = (unsigned short*)d_ws;
    unsigned short* frags = (unsigned short*)((char*)d_ws + kFragOff);
    float* melT           = (float*)((char*)d_ws + kMelTOff);
    unsigned short* power = (unsigned short*)((char*)d_ws + kPowOff);

    prep_y<<<dim3((kYPad + 255) / 256, kBatch), 256, 0, stream>>>(x, ypad);
    prep_frags<<<dim3(131072 / 256), 256, 0, stream>>>(basis, frags);
    prep_melT<<<dim3((513 * 128 + 255) / 256), 256, 0, stream>>>(melb, melT);
    stft_power<<<dim3(8, 8, kBatch), 256, 0, stream>>>(frags, ypad, power);
    mel_log<<<dim3(32, kBatch), 256, 0, stream>>>(power, melT, out);
}

// Round 3
// 276.424 us; speedup vs baseline: 6.3656x; 1.9436x over previous
//
#include <hip/hip_runtime.h>
#include <math.h>

typedef _Float16 half8 __attribute__((ext_vector_type(8)));
typedef float f32x4 __attribute__((ext_vector_type(4)));

constexpr int kNFFT    = 1024;
constexpr int kHop     = 320;
constexpr int kMels    = 128;
constexpr int kFrames  = 1000;
constexpr int kBatch   = 32;
constexpr int kXLen    = 320000;
constexpr int kYLen    = kXLen - 1;          // 319999
constexpr int kYPad    = 328704;             // >= 1023*320+1024, mult of 256
constexpr int kYOff    = 512;                // center-pad offset
constexpr float kPre   = 0.97f;
constexpr int kPStride = 544;                // power row stride (bins padded 513->544)

// ws layout (element offsets in _Float16 units where noted)
constexpr size_t kYLvl     = (size_t)kBatch * kYPad;            // halfs per level
constexpr size_t kFragLvl  = 64ull * 32 * 64 * 8;               // halfs per level = 1,048,576
constexpr size_t kFragOff  = 2 * kYLvl;                         // after 2 y levels
constexpr size_t kMelFrOff = kFragOff + 2 * kFragLvl;
constexpr size_t kMelFrSz  = 8ull * 17 * 64 * 8;                // 69,632 halfs
constexpr size_t kPowOff   = kMelFrOff + kMelFrSz;              // halfs
constexpr size_t kPowSz    = (size_t)kBatch * 1024 * kPStride;  // 17,825,792 halfs

struct alignas(8) h4 { _Float16 v[4]; };

// ---- prep 1: pre-emphasis + center pad, 2-level f16 split ----
__global__ void prep_y(const float* __restrict__ x, _Float16* __restrict__ yp) {
    int i = blockIdx.x * 256 + threadIdx.x;
    if (i >= kYPad) return;
    int b = blockIdx.y;
    int yi = i - kYOff;
    float v = 0.0f;
    if (yi >= 0 && yi < kYLen) {
        const float* xb = x + (size_t)b * kXLen;
        v = xb[yi + 1] - kPre * xb[yi];
    }
    _Float16 h = (_Float16)v;
    _Float16 m = (_Float16)(v - (float)h);
    size_t idx = (size_t)b * kYPad + i;
    yp[idx] = h;
    yp[idx + kYLvl] = m;
}

// ---- prep 2: fourier basis -> MFMA A-fragments, 2-level f16 split ----
// packed rows: 0..512 = cos bins 0..512; 513..1023 = sin bins 1..511 (orig r+1)
// frag[lv][g][ks][lane][j] : A[m=lane&15 (in group g)][k=32ks+(lane>>4)*8+j]
__global__ void prep_frags(const float* __restrict__ basis, _Float16* __restrict__ fr) {
    int id = blockIdx.x * 256 + threadIdx.x;      // < 131072
    int L  = id & 63;
    int ks = (id >> 6) & 31;
    int g  = id >> 11;                            // 0..63
    int r  = 16 * g + (L & 15);
    int orig = (r <= 512) ? r : r + 1;
    const float* src = basis + (size_t)orig * kNFFT + 32 * ks + (L >> 4) * 8;
    _Float16* dst = fr + (size_t)id * 8;          // id == (g*32+ks)*64+L
    #pragma unroll
    for (int j = 0; j < 8; ++j) {
        float a = src[j];
        _Float16 h = (_Float16)a;
        _Float16 m = (_Float16)(a - (float)h);
        dst[j] = h;
        dst[j + kFragLvl] = m;
    }
}

// ---- prep 3: mel basis -> MFMA A-fragments, f16, K padded 513->544 ----
__global__ void prep_melfr(const float* __restrict__ melb, _Float16* __restrict__ fr) {
    int id = blockIdx.x * 256 + threadIdx.x;
    if (id >= 8 * 17 * 64) return;
    int f = id / 1088;
    int rem = id - f * 1088;
    int ks = rem >> 6;
    int L = rem & 63;
    int m = 16 * f + (L & 15);
    int kb = 32 * ks + (L >> 4) * 8;
    _Float16* dst = fr + (size_t)id * 8;
    #pragma unroll
    for (int j = 0; j < 8; ++j) {
        int k = kb + j;
        dst[j] = (k < 513) ? (_Float16)melb[(size_t)m * 513 + k] : (_Float16)0.0f;
    }
}

// ---- main: 3-term split-f16 MFMA STFT + power ----
// block: (nt, g, b). rows {64g..64g+63} U {512+64g..}; N = 256 frames.
// wave tile M=128 x N=64. power[b][t(1024)][bin(544 pad)] f16.
__global__ __launch_bounds__(256, 2)
void stft_power(const _Float16* __restrict__ frags,
                const _Float16* __restrict__ ypad,
                _Float16* __restrict__ pw) {
    __shared__ __align__(16) _Float16 ash[16 * 512];   // 16 frags x 1KB
    const int tid  = threadIdx.x;
    const int w    = tid >> 6;
    const int lane = tid & 63;
    const int quad = lane >> 4;
    const int l16  = lane & 15;
    const int nt = blockIdx.x, g = blockIdx.y, b = blockIdx.z;
    const int t0 = nt * 256 + w * 64;

    const _Float16* yb0 = ypad + (size_t)b * kYPad;
    const _Float16* yb1 = yb0 + kYLvl;

    f32x4 acc[8][4] = {};

    for (int ks = 0; ks < 32; ++ks) {
        __syncthreads();
        // stage 16 A-frags (8 f x 2 lvl): wave w handles slots {w, w+4, w+8, w+12}
        #pragma unroll
        for (int c = 0; c < 4; ++c) {
            int slot = w + 4 * c;
            int f = slot & 7;
            int lv = slot >> 3;
            int Gf = (f < 4) ? (4 * g + f) : (32 + 4 * g + (f - 4));
            const _Float16* gp = frags + (size_t)lv * kFragLvl
                                 + ((size_t)(Gf * 32 + ks) * 64 + lane) * 8;
            __builtin_amdgcn_global_load_lds(
                (const __attribute__((address_space(1))) void*)gp,
                (__attribute__((address_space(3))) void*)&ash[slot * 512],
                16, 0, 0);
        }
        // B fragments direct from L2
        half8 bh[4], bm[4];
        #pragma unroll
        for (int nf = 0; nf < 4; ++nf) {
            int off = (t0 + nf * 16 + l16) * kHop + ks * 32 + quad * 8;
            bh[nf] = *(const half8*)(yb0 + off);
            bm[nf] = *(const half8*)(yb1 + off);
        }
        __syncthreads();
        #pragma unroll
        for (int f = 0; f < 8; ++f) {
            half8 afh = *(const half8*)&ash[f * 512 + lane * 8];
            half8 afm = *(const half8*)&ash[(8 + f) * 512 + lane * 8];
            #pragma unroll
            for (int nf = 0; nf < 4; ++nf) {
                f32x4 a = acc[f][nf];
                a = __builtin_amdgcn_mfma_f32_16x16x32_f16(afh, bh[nf], a, 0, 0, 0);
                a = __builtin_amdgcn_mfma_f32_16x16x32_f16(afh, bm[nf], a, 0, 0, 0);
                a = __builtin_amdgcn_mfma_f32_16x16x32_f16(afm, bh[nf], a, 0, 0, 0);
                acc[f][nf] = a;
            }
        }
    }

    // epilogue: power = cos^2 + sin^2; chunk f (cos) pairs with f+4 (sin, same bin)
    #pragma unroll
    for (int mf = 0; mf < 4; ++mf) {
        int b0 = 64 * g + 16 * mf + 4 * quad;
        #pragma unroll
        for (int nf = 0; nf < 4; ++nf) {
            int t = t0 + nf * 16 + l16;
            size_t row = ((size_t)((b << 10) + t)) * kPStride;
            h4 pp;
            #pragma unroll
            for (int r = 0; r < 4; ++r) {
                float pA = acc[mf][nf][r];
                float pB = acc[4 + mf][nf][r];
                float p2 = pA * pA + pB * pB;
                if (g == 0 && mf == 0 && quad == 0 && r == 0) {
                    // packed row 0 = cos bin 0 (sin==0); paired row 512 = cos bin 512
                    p2 = pA * pA;
                    pw[row + 512] = (_Float16)(pB * pB);
                }
                pp.v[r] = (_Float16)p2;
            }
            *(h4*)&pw[row + b0] = pp;
        }
    }
}

// ---- mel + log via MFMA: out[b][m][t] = (log(mel+1e-5)+4.5)/5 ----
// block: (nt, b), 4 waves, N=128 frames (wave 32), M=128 mels, K=544.
__global__ __launch_bounds__(256)
void mel_mfma(const _Float16* __restrict__ melfr, const _Float16* __restrict__ pw,
              float* __restrict__ out) {
    const int tid  = threadIdx.x;
    const int w    = tid >> 6;
    const int lane = tid & 63;
    const int quad = lane >> 4;
    const int l16  = lane & 15;
    const int nt = blockIdx.x, b = blockIdx.y;
    const int t0 = nt * 128 + w * 32;

    f32x4 acc[8][2] = {};
    for (int ks = 0; ks < 17; ++ks) {
        half8 bp[2];
        #pragma unroll
        for (int nf = 0; nf < 2; ++nf) {
            int t = t0 + nf * 16 + l16;
            bp[nf] = *(const half8*)(pw + ((size_t)((b << 10) + t)) * kPStride
                                     + 32 * ks + quad * 8);
        }
        #pragma unroll
        for (int f = 0; f < 8; ++f) {
            half8 af = *(const half8*)(melfr + ((size_t)(f * 17 + ks) * 64 + lane) * 8);
            #pragma unroll
            for (int nf = 0; nf < 2; ++nf)
                acc[f][nf] = __builtin_amdgcn_mfma_f32_16x16x32_f16(af, bp[nf], acc[f][nf], 0, 0, 0);
        }
    }
    #pragma unroll
    for (int f = 0; f < 8; ++f) {
        #pragma unroll
        for (int nf = 0; nf < 2; ++nf) {
            int t = t0 + nf * 16 + l16;
            if (t < kFrames) {
                #pragma unroll
                for (int r = 0; r < 4; ++r) {
                    int m = 16 * f + 4 * quad + r;
                    out[((size_t)(b * kMels + m)) * kFrames + t] =
                        (__logf(acc[f][nf][r] + 1e-5f) + 4.5f) * 0.2f;
                }
            }
        }
    }
}

extern "C" void kernel_launch(void* const* d_in, const int* in_sizes, int n_in,
                              void* d_out, int out_size, void* d_ws, size_t ws_size,
                              hipStream_t stream) {
    const float* x     = (const float*)d_in[0];
    const float* basis = (const float*)d_in[1];
    const float* melb  = (const float*)d_in[2];
    float* out = (float*)d_out;

    _Float16* ws    = (_Float16*)d_ws;
    _Float16* ypad  = ws;
    _Float16* frags = ws + kFragOff;
    _Float16* melfr = ws + kMelFrOff;
    _Float16* pw    = ws + kPowOff;

    prep_y<<<dim3((kYPad + 255) / 256, kBatch), 256, 0, stream>>>(x, ypad);
    prep_frags<<<dim3(131072 / 256), 256, 0, stream>>>(basis, frags);
    prep_melfr<<<dim3((8 * 17 * 64 + 255) / 256), 256, 0, stream>>>(melb, melfr);
    stft_power<<<dim3(4, 8, kBatch), 256, 0, stream>>>(frags, ypad, pw);
    mel_mfma<<<dim3(8, kBatch), 256, 0, stream>>>(melfr, pw, out);
}